// Round 3
// baseline (151.774 us; speedup 1.0000x reference)
//
#include <hip/hip_runtime.h>

// N=16384 rows, D=1024 fp32. loss = mean_r(1 - cos(pc[r], aug[r]))
// R1/R2: 42us @ 3.15 TB/s effective regardless of occupancy/rows-per-wave.
// Suspect: per-row shfl-reduction tail (18 dependent ds_bpermute, ~120cyc
// LDS latency each) + barrier serialize against the load stream.
// R3: pure-streaming partial kernel (no shfl/LDS/barrier) -> 3MB partials in
// ws, then tiny reduce kernels.

#define N_ROWS 16384
#define ROW_V4 256               // 1024 floats = 256 float4 per row
#define SEGS 16                  // segments per row
#define SEG_V4 16                // float4 per segment (64 floats)
#define TPB 256
#define NPART (N_ROWS * SEGS)    // 262144 partial triples
#define BLOCKS1 (NPART / TPB)    // 1024 blocks
#define BLOCKS2 256              // 64 rows per block

// Kernel 1: pure streaming. thread g -> row = g>>4, seg = g&15.
// Per j, a wave's 64 lanes cover 4 rows x 16 consecutive float4 -> 4
// contiguous 256B chunks per load instruction (8x128B lines, fully packed).
__global__ __launch_bounds__(TPB) void partial_kernel(
    const float4* __restrict__ a, const float4* __restrict__ b,
    float* __restrict__ ab_ws, float* __restrict__ aa_ws,
    float* __restrict__ bb_ws)
{
    const int g = blockIdx.x * TPB + threadIdx.x;
    const int row = g >> 4;
    const int seg = g & (SEGS - 1);
    const float4* ap = a + (size_t)row * ROW_V4 + seg;
    const float4* bp = b + (size_t)row * ROW_V4 + seg;

    float ab = 0.0f, aa = 0.0f, bb = 0.0f;
    #pragma unroll
    for (int j = 0; j < SEG_V4; ++j) {
        float4 x = ap[j * SEGS];
        float4 y = bp[j * SEGS];
        ab += x.x * y.x + x.y * y.y + x.z * y.z + x.w * y.w;
        aa += x.x * x.x + x.y * x.y + x.z * x.z + x.w * x.w;
        bb += y.x * y.y == 0.0f ? y.x * y.x + y.y * y.y + y.z * y.z + y.w * y.w
                                : y.x * y.x + y.y * y.y + y.z * y.z + y.w * y.w;
    }
    ab_ws[g] = ab;
    aa_ws[g] = aa;
    bb_ws[g] = bb;
}

// Kernel 2: block b handles 64 rows (1024 partials per array), computes cos
// per row on wave 0, then reduces to one partial per block.
__global__ __launch_bounds__(TPB) void rowcos_kernel(
    const float* __restrict__ ab_ws, const float* __restrict__ aa_ws,
    const float* __restrict__ bb_ws, float* __restrict__ partial)
{
    __shared__ float sab[1024], saa[1024], sbb[1024];
    const int base = blockIdx.x * 1024;
    #pragma unroll
    for (int i = threadIdx.x; i < 1024; i += TPB) {
        sab[i] = ab_ws[base + i];
        saa[i] = aa_ws[base + i];
        sbb[i] = bb_ws[base + i];
    }
    __syncthreads();

    float t = 0.0f;
    if (threadIdx.x < 64) {
        const int r = threadIdx.x;
        float ab = 0.0f, aa = 0.0f, bb = 0.0f;
        #pragma unroll
        for (int i = 0; i < SEGS; ++i) {
            ab += sab[r * SEGS + i];
            aa += saa[r * SEGS + i];
            bb += sbb[r * SEGS + i];
        }
        float na = fmaxf(sqrtf(aa), 1e-12f);
        float nb = fmaxf(sqrtf(bb), 1e-12f);
        t = ab / (na * nb);
    }
    if (threadIdx.x < 64) {
        #pragma unroll
        for (int off = 32; off > 0; off >>= 1) t += __shfl_down(t, off);
        if (threadIdx.x == 0) partial[blockIdx.x] = t;
    }
}

// Kernel 3: reduce 256 block partials -> scalar loss.
__global__ __launch_bounds__(TPB) void finalize_kernel(
    const float* __restrict__ partial, float* __restrict__ out)
{
    const int wave = threadIdx.x >> 6;
    const int lane = threadIdx.x & 63;
    float t = partial[threadIdx.x];
    #pragma unroll
    for (int off = 32; off > 0; off >>= 1) t += __shfl_down(t, off);
    __shared__ float s[TPB / 64];
    if (lane == 0) s[wave] = t;
    __syncthreads();
    if (threadIdx.x == 0) {
        float tot = 0.0f;
        #pragma unroll
        for (int i = 0; i < TPB / 64; ++i) tot += s[i];
        out[0] = 1.0f - tot / (float)N_ROWS;
    }
}

extern "C" void kernel_launch(void* const* d_in, const int* in_sizes, int n_in,
                              void* d_out, int out_size, void* d_ws, size_t ws_size,
                              hipStream_t stream) {
    const float4* pc  = (const float4*)d_in[0];
    const float4* aug = (const float4*)d_in[1];
    float* ab_ws = (float*)d_ws;                 // NPART floats
    float* aa_ws = ab_ws + NPART;                // NPART floats
    float* bb_ws = aa_ws + NPART;                // NPART floats
    float* partial = bb_ws + NPART;              // BLOCKS2 floats
    float* out = (float*)d_out;

    partial_kernel<<<BLOCKS1, TPB, 0, stream>>>(pc, aug, ab_ws, aa_ws, bb_ws);
    rowcos_kernel<<<BLOCKS2, TPB, 0, stream>>>(ab_ws, aa_ws, bb_ws, partial);
    finalize_kernel<<<1, TPB, 0, stream>>>(partial, out);
}

// Round 4
// 144.683 us; speedup vs baseline: 1.0490x; 1.0490x over previous
//
#include <hip/hip_runtime.h>

// N=16384 rows, D=1024 fp32. loss = mean_r(1 - cos(pc[r], aug[r]))
// R1-R3: ~42-46us @ ~3.2 TB/s effective, invariant to occupancy, rows/wave,
// and even HBM-vs-L3 residence (L3-warm replay = same time). Common factor:
// VGPR_Count 24-28 -> compiler kept only ~2 loads in flight per wave.
// R4: force 16 independent float4 loads per lane (256B in flight) held in
// explicit registers before any consumption. 2 row-pairs per wave.

#define N_ROWS 16384
#define ROW_V4 256               // 1024 floats = 256 float4 per row
#define TPB 256
#define WPB (TPB / 64)           // 4 waves per block
#define ROWS_PER_WAVE 2
#define BLOCKS (N_ROWS / (WPB * ROWS_PER_WAVE))   // 2048 blocks

__global__ __launch_bounds__(TPB) void cos_rows_kernel(
    const float4* __restrict__ a, const float4* __restrict__ b,
    float* __restrict__ partial)
{
    const int wave = threadIdx.x >> 6;
    const int lane = threadIdx.x & 63;
    const int r0 = (blockIdx.x * WPB + wave) * ROWS_PER_WAVE;

    const float4* a0 = a + (size_t)r0 * ROW_V4 + lane;
    const float4* b0 = b + (size_t)r0 * ROW_V4 + lane;

    // 16 independent loads, all issued before any consumption.
    float4 x[8], y[8];
    #pragma unroll
    for (int k = 0; k < 4; ++k) x[k]     = a0[64 * k];
    #pragma unroll
    for (int k = 0; k < 4; ++k) x[4 + k] = a0[ROW_V4 + 64 * k];
    #pragma unroll
    for (int k = 0; k < 4; ++k) y[k]     = b0[64 * k];
    #pragma unroll
    for (int k = 0; k < 4; ++k) y[4 + k] = b0[ROW_V4 + 64 * k];

    float ab0 = 0, aa0 = 0, bb0 = 0, ab1 = 0, aa1 = 0, bb1 = 0;
    #pragma unroll
    for (int k = 0; k < 4; ++k) {
        ab0 += x[k].x * y[k].x + x[k].y * y[k].y + x[k].z * y[k].z + x[k].w * y[k].w;
        aa0 += x[k].x * x[k].x + x[k].y * x[k].y + x[k].z * x[k].z + x[k].w * x[k].w;
        bb0 += y[k].x * y[k].x + y[k].y * y[k].y + y[k].z * y[k].z + y[k].w * y[k].w;
    }
    #pragma unroll
    for (int k = 4; k < 8; ++k) {
        ab1 += x[k].x * y[k].x + x[k].y * y[k].y + x[k].z * y[k].z + x[k].w * y[k].w;
        aa1 += x[k].x * x[k].x + x[k].y * x[k].y + x[k].z * x[k].z + x[k].w * x[k].w;
        bb1 += y[k].x * y[k].x + y[k].y * y[k].y + y[k].z * y[k].z + y[k].w * y[k].w;
    }

    // Butterfly reductions on 6 independent values.
    #pragma unroll
    for (int off = 32; off > 0; off >>= 1) {
        ab0 += __shfl_down(ab0, off);
        aa0 += __shfl_down(aa0, off);
        bb0 += __shfl_down(bb0, off);
        ab1 += __shfl_down(ab1, off);
        aa1 += __shfl_down(aa1, off);
        bb1 += __shfl_down(bb1, off);
    }

    __shared__ float s[WPB];
    if (lane == 0) {
        float c0 = ab0 / (fmaxf(sqrtf(aa0), 1e-12f) * fmaxf(sqrtf(bb0), 1e-12f));
        float c1 = ab1 / (fmaxf(sqrtf(aa1), 1e-12f) * fmaxf(sqrtf(bb1), 1e-12f));
        s[wave] = c0 + c1;
    }
    __syncthreads();
    if (threadIdx.x == 0) {
        float t = 0.0f;
        #pragma unroll
        for (int i = 0; i < WPB; ++i) t += s[i];
        partial[blockIdx.x] = t;
    }
}

__global__ __launch_bounds__(1024) void finalize_kernel(
    const float* __restrict__ partial, float* __restrict__ out)
{
    const int wave = threadIdx.x >> 6;
    const int lane = threadIdx.x & 63;
    float t = 0.0f;
    #pragma unroll
    for (int i = 0; i < BLOCKS / 1024; ++i) t += partial[threadIdx.x + 1024 * i];
    #pragma unroll
    for (int off = 32; off > 0; off >>= 1) t += __shfl_down(t, off);
    __shared__ float s[1024 / 64];
    if (lane == 0) s[wave] = t;
    __syncthreads();
    if (threadIdx.x == 0) {
        float tot = 0.0f;
        #pragma unroll
        for (int i = 0; i < 1024 / 64; ++i) tot += s[i];
        out[0] = 1.0f - tot / (float)N_ROWS;
    }
}

extern "C" void kernel_launch(void* const* d_in, const int* in_sizes, int n_in,
                              void* d_out, int out_size, void* d_ws, size_t ws_size,
                              hipStream_t stream) {
    const float4* pc  = (const float4*)d_in[0];
    const float4* aug = (const float4*)d_in[1];
    float* partial = (float*)d_ws;       // BLOCKS floats = 8 KiB scratch
    float* out = (float*)d_out;

    cos_rows_kernel<<<BLOCKS, TPB, 0, stream>>>(pc, aug, partial);
    finalize_kernel<<<1, 1024, 0, stream>>>(partial, out);
}